// Round 8
// baseline (161.661 us; speedup 1.0000x reference)
//
#include <hip/hip_runtime.h>
#include <math.h>

#define KGT   16
#define NCAND 9
#define NLVL  5
#define NPRI  8525
#define NCLS  80
#define NIMG  32

#define FOCAL_BLOCKS 2016
#define TOTAL_BLOCKS (FOCAL_BLOCKS + NIMG)   // 2048
#define NELEM (NIMG * NPRI * NCLS)           // 21,824,000
#define N4    (NELEM / 4)                    // 5,456,000 float4s
#define CHUNK 2707                           // ceil(N4 / FOCAL_BLOCKS); 11 rounds of 256
#define NROUND 11

// ws: partials @ 0 (2016 f32), imgstats @ 8192 (32 x {corr,loc,cnt} f32).
// Both fully written every call — no init required.
#define OFF_IMG 8192

__device__ __forceinline__ float focal_elem(float x)
{
    float e  = __expf(-fabsf(x));                 // e^{-|x|}
    float t  = 1.f + e;
    float r  = __builtin_amdgcn_rcpf(t);          // ~1ulp rcp (2% output tolerance)
    float sp = fmaxf(x, 0.f) + __logf(t);         // softplus(x)
    float nm = (x >= 0.f) ? 1.f : e;
    float p  = nm * r;                            // sigmoid(x)
    return p * p * sp;
}

__device__ __forceinline__ float focal4(float4 v)
{
    return focal_elem(v.x) + focal_elem(v.y) + focal_elem(v.z) + focal_elem(v.w);
}

// ------------------------------------------------------------------ kernel 1
// blocks [0, 2016): focal partial sums; async global->LDS staging, 3-deep
// blocks [2016, 2048): per-image scan (5x5 window) + decide (arena overlaid)
__global__ __launch_bounds__(256)
void atss_main(const float* __restrict__ locs,
               const float* __restrict__ scores,
               const float* __restrict__ boxes,
               const int*   __restrict__ labels,
               const float* __restrict__ priors,
               float* __restrict__ partials,
               float* __restrict__ imgstats)
{
    const int tid = threadIdx.x;
    const int blk = blockIdx.x;

    __shared__ float4 stage[3][256];   // 12 KB: focal staging / decide arena
    __shared__ float wsum[4];
    __shared__ float rc, rl;
    __shared__ int   rn;

    if (blk < FOCAL_BLOCKS) {
        // ---------- focal base: sum p^2*softplus(x), DMA-staged via LDS ----------
        const float4* s4 = (const float4*)scores;
        const int cbase = blk * CHUNK;
        const int w = tid >> 6, lane = tid & 63;
        const int wslice = w << 6;                // this wave's 64-float4 LDS slice

        // round k stages float4s [cbase + k*256, +256) into stage[k%3];
        // wave w's slice: global cbase + k*256 + w*64 + lane -> lds slice + lane*16.
        // Per-wave private slices => no __syncthreads anywhere in the pipeline.
        #define ISSUE(k)                                                            \
            do {                                                                    \
                int gi_ = min(cbase + (k) * 256 + wslice + lane, N4 - 1);           \
                __builtin_amdgcn_global_load_lds(                                   \
                    (const __attribute__((address_space(1))) void*)(s4 + gi_),      \
                    (__attribute__((address_space(3))) void*)&stage[(k) % 3][wslice],\
                    16, 0, 0);                                                      \
            } while (0)

        ISSUE(0); ISSUE(1); ISSUE(2);

        float a0 = 0.f, a1 = 0.f;
        #pragma unroll
        for (int k = 0; k < NROUND; ++k) {
            __builtin_amdgcn_s_waitcnt(0x0F72);   // vmcnt(2): round k staged
            float4 v = stage[k % 3][wslice + lane];
            __asm__ volatile("" ::: "memory");    // keep next ISSUE below the read
            if (k + 3 < NROUND) ISSUE(k + 3);
            // validity: k<=9 always inside chunk; k==10 iff tid<CHUNK-2560 (=147);
            // last block additionally clamped against N4.
            bool vld = (k * 256 + tid < CHUNK) && (cbase + k * 256 + tid < N4);
            float tv = focal4(v);
            if (k & 1) a1 += vld ? tv : 0.f;
            else       a0 += vld ? tv : 0.f;
        }
        #undef ISSUE

        float lsum = a0 + a1;
        #pragma unroll
        for (int off = 32; off > 0; off >>= 1) lsum += __shfl_down(lsum, off);
        if ((tid & 63) == 0) wsum[tid >> 6] = lsum;
        __syncthreads();
        if (tid == 0)
            partials[blk] = wsum[0] + wsum[1] + wsum[2] + wsum[3];
        return;
    }

    // ---------------- scan + decide for image b, entirely block-local ----------
    const int b = blk - FOCAL_BLOCKS;
    const int SPLc[6] = {0, 6400, 8000, 8400, 8500, 8525};
    const int FDIM[5] = {80, 40, 20, 10, 5};

    float* arena = (float*)stage;          // 3072 floats available
    float* pov  = arena;                   // [KGT*45]
    int*   tix  = (int*)(arena + 720);     // [KGT*45]
    float* sbox = arena + 1440;            // [KGT*4]
    int*   slab = (int*)(arena + 1504);    // [KGT]
    float* thr  = arena + 1520;            // [KGT]

    if (tid == 0) { rc = 0.f; rl = 0.f; rn = 0; }
    if (tid < KGT) {
        float4 bxv = ((const float4*)boxes)[b * KGT + tid];
        sbox[tid * 4 + 0] = bxv.x; sbox[tid * 4 + 1] = bxv.y;
        sbox[tid * 4 + 2] = bxv.z; sbox[tid * 4 + 3] = bxv.w;
        slab[tid] = labels[b * KGT + tid];
    }
    __syncthreads();

    // Stage 1: one thread per (gt, level): top-9 via 5x5 grid window.
    // Priors of level l form a regular f x f grid, spacing 1/f: the 9 nearest
    // centers lie in the 5x5 window of nearest rows/cols (9th-nearest <= ~1.6/f,
    // anything outside >= 2.5/f).
    if (tid < KGT * NLVL) {
        const int g = tid / NLVL;
        const int l = tid % NLVL;
        const int f    = FDIM[l];
        const int base = SPLc[l];
        const float gcx = (sbox[g * 4 + 0] + sbox[g * 4 + 2]) * 0.5f;
        const float gcy = (sbox[g * 4 + 1] + sbox[g * 4 + 3]) * 0.5f;

        const float ff = (float)f;
        int ix0 = (int)floorf(gcx * ff); ix0 = min(max(ix0, 0), f - 1);
        int iy0 = (int)floorf(gcy * ff); iy0 = min(max(iy0, 0), f - 1);
        int sx = min(max(ix0 - 2, 0), f - 5);
        int sy = min(max(iy0 - 2, 0), f - 5);

        unsigned long long L[NCAND];
        #pragma unroll
        for (int s = 0; s < NCAND; ++s) L[s] = ~0ull;

        for (int dy = 0; dy < 5; ++dy) {
            for (int dx = 0; dx < 5; ++dx) {
                int idx = (sy + dy) * f + (sx + dx);
                float2 pc = ((const float2*)priors)[(base + idx) * 2];
                float ddx = gcx - pc.x, ddy = gcy - pc.y;
                float dist = sqrtf(ddx * ddx + ddy * ddy);  // matches ref rounding
                unsigned long long pk =
                    ((unsigned long long)__float_as_uint(dist) << 32) | (unsigned)idx;
                if (pk < L[NCAND - 1]) {            // lexicographic (dist, idx)
                    L[NCAND - 1] = pk;
                    #pragma unroll
                    for (int s = NCAND - 1; s >= 1; --s) {
                        if (L[s] < L[s - 1]) {
                            unsigned long long tw = L[s]; L[s] = L[s - 1]; L[s - 1] = tw;
                        } else break;
                    }
                }
            }
        }
        // ascending (dist, idx) == lax.top_k order; emit IoU per candidate
        #pragma unroll
        for (int s = 0; s < NCAND; ++s) {
            int idx = (int)(unsigned)(L[s] & 0xffffffffull);
            float4 pr = ((const float4*)priors)[base + idx];
            float px0 = pr.x - pr.z * 0.5f, py0 = pr.y - pr.w * 0.5f;
            float px1 = pr.x + pr.z * 0.5f, py1 = pr.y + pr.w * 0.5f;
            float iw = fmaxf(fminf(sbox[g*4+2], px1) - fmaxf(sbox[g*4+0], px0), 0.f);
            float ih = fmaxf(fminf(sbox[g*4+3], py1) - fmaxf(sbox[g*4+1], py0), 0.f);
            float inter = iw * ih;
            float areaA = (sbox[g*4+2] - sbox[g*4+0]) * (sbox[g*4+3] - sbox[g*4+1]);
            float areaP = (px1 - px0) * (py1 - py0);
            int o = g * 45 + l * NCAND + s;
            pov[o] = inter / (areaA + areaP - inter);
            tix[o] = idx;
        }
    }
    __syncthreads();

    // Stage 2: adaptive threshold = mean + std(ddof=1) over each GT's 45 IoUs
    if (tid < KGT) {
        float s = 0.f;
        for (int q = 0; q < 45; ++q) s += pov[tid * 45 + q];
        float mean = s / 45.f;
        float ss = 0.f;
        for (int q = 0; q < 45; ++q) { float d = pov[tid * 45 + q] - mean; ss += d * d; }
        thr[tid] = mean + sqrtf(ss / 44.f);
    }
    __syncthreads();

    // Stage 3: per (level, cand): argmax over GTs, focal correction + CIoU
    if (tid < NLVL * NCAND) {
        int l = tid / NCAND, j = tid % NCAND;
        float bestv = -1.f; int bestg = 0;
        #pragma unroll
        for (int gg = 0; gg < KGT; ++gg) {
            float m = pov[gg * 45 + tid];
            int pi = tix[gg * 45 + tid];
            float4 pr = ((const float4*)priors)[SPLc[l] + pi];
            bool inside = (sbox[gg*4+0] < pr.x) && (pr.x < sbox[gg*4+2]) &&
                          (sbox[gg*4+1] < pr.y) && (pr.y < sbox[gg*4+3]);
            float mm = ((m > thr[gg]) && inside) ? m : 0.f;
            if (mm > bestv) { bestv = mm; bestg = gg; }   // first max wins
        }
        if (bestv > 0.f) {
            int lab = slab[bestg];
            // focal correction at prior SPL[l]+j, class lab (ref's .at[arange(9)] quirk)
            long pos = (long)b * NPRI + SPLc[l] + j;
            float x  = scores[pos * NCLS + (lab - 1)];
            float e  = expf(-fabsf(x));
            float l1 = log1pf(e);
            float spp = fmaxf(x, 0.f) + l1;
            float spn = fmaxf(-x, 0.f) + l1;
            float p   = (x >= 0.f) ? 1.f / (1.f + e) : e / (1.f + e);
            float corr = 0.25f * (1.f - p) * (1.f - p) * spn - 0.75f * p * p * spp;

            // decode pred box at matched prior, CIoU vs gt
            int pi = tix[bestg * 45 + tid];
            float4 pr = ((const float4*)priors)[SPLc[l] + pi];
            float4 lc = ((const float4*)locs)[b * NPRI + SPLc[l] + pi];
            float cx = lc.x * pr.z / 10.f + pr.x;
            float cy = lc.y * pr.w / 10.f + pr.y;
            float w  = expf(lc.z / 5.f) * pr.z;
            float h  = expf(lc.w / 5.f) * pr.w;
            float qx0 = cx - w * 0.5f, qy0 = cy - h * 0.5f;
            float qx1 = cx + w * 0.5f, qy1 = cy + h * 0.5f;
            float gx0 = sbox[bestg*4+0], gy0 = sbox[bestg*4+1];
            float gx1 = sbox[bestg*4+2], gy1 = sbox[bestg*4+3];
            float w1 = qx1 - qx0, h1 = qy1 - qy0, w2 = gx1 - gx0, h2 = gy1 - gy0;
            float iw = fmaxf(fminf(qx1, gx1) - fmaxf(qx0, gx0), 0.f);
            float ih = fmaxf(fminf(qy1, gy1) - fmaxf(qy0, gy0), 0.f);
            float inter = iw * ih;
            float iou = inter / (w1 * h1 + w2 * h2 - inter);
            float dcx = (qx0 + qx1) * 0.5f - (gx0 + gx1) * 0.5f;
            float dcy = (qy0 + qy1) * 0.5f - (gy0 + gy1) * 0.5f;
            float rho2 = dcx * dcx + dcy * dcy;
            float ex = fmaxf(qx1, gx1) - fminf(qx0, gx0);
            float ey = fmaxf(qy1, gy1) - fminf(qy0, gy0);
            float cdiag = ex * ex + ey * ey;
            float da = atanf(w2 / h2) - atanf(w1 / h1);
            float v  = 0.4052847345693511f * da * da;     // 4/pi^2
            float alpha = v / (1.f - iou + v);
            float ci = iou - rho2 / cdiag - alpha * v;
            ci = fminf(fmaxf(ci, -1.f), 1.f);

            atomicAdd(&rc, corr);       // LDS atomics, block-local
            atomicAdd(&rl, 1.f - ci);
            atomicAdd(&rn, 1);
        }
    }
    __syncthreads();
    if (tid == 0) {
        imgstats[b * 3 + 0] = rc;
        imgstats[b * 3 + 1] = rl;
        imgstats[b * 3 + 2] = (float)rn;
    }
}

// ------------------------------------------------------------------ kernel 2
__global__ __launch_bounds__(256)
void atss_finalize(const float* __restrict__ partials,
                   const float* __restrict__ imgstats,
                   float* __restrict__ out)
{
    const int tid = threadIdx.x;
    __shared__ float wsum[4];
    float lsum = 0.f;
    for (int i = tid; i < FOCAL_BLOCKS; i += 256) lsum += partials[i];
    #pragma unroll
    for (int off = 32; off > 0; off >>= 1) lsum += __shfl_down(lsum, off);
    if ((tid & 63) == 0) wsum[tid >> 6] = lsum;
    __syncthreads();
    if (tid == 0) {
        float base = 0.75f * (wsum[0] + wsum[1] + wsum[2] + wsum[3]);
        float corr = 0.f, loc = 0.f, cnt = 0.f;
        for (int b = 0; b < NIMG; ++b) {
            corr += imgstats[b * 3 + 0];
            loc  += imgstats[b * 3 + 1];
            cnt  += imgstats[b * 3 + 2];
        }
        float conf = (base + corr) / cnt;            // ref: / n_pos (no clamp)
        float locl = loc / fmaxf(cnt, 1.f);          // ref: clamped denom
        out[0] = conf + locl;
    }
}

extern "C" void kernel_launch(void* const* d_in, const int* in_sizes, int n_in,
                              void* d_out, int out_size, void* d_ws, size_t ws_size,
                              hipStream_t stream)
{
    const float* locs   = (const float*)d_in[0];   // (32, 8525, 4)
    const float* scores = (const float*)d_in[1];   // (32, 8525, 80)
    const float* boxes  = (const float*)d_in[2];   // (32, 16, 4)
    const int*   labels = (const int*)d_in[3];     // (32, 16)
    const float* priors = (const float*)d_in[4];   // (8525, 4)
    float* out = (float*)d_out;

    float* partials = (float*)d_ws;
    float* imgstats = (float*)((char*)d_ws + OFF_IMG);

    atss_main<<<TOTAL_BLOCKS, 256, 0, stream>>>(locs, scores, boxes, labels,
                                                priors, partials, imgstats);
    atss_finalize<<<1, 256, 0, stream>>>(partials, imgstats, out);
}

// Round 9
// 155.165 us; speedup vs baseline: 1.0419x; 1.0419x over previous
//
#include <hip/hip_runtime.h>
#include <math.h>

#define KGT   16
#define NCAND 9
#define NLVL  5
#define NPRI  8525
#define NCLS  80
#define NIMG  32

#define FOCAL_BLOCKS 2016
#define TOTAL_BLOCKS (FOCAL_BLOCKS + NIMG)   // 2048
#define NELEM (NIMG * NPRI * NCLS)           // 21,824,000
#define N4    (NELEM / 4)                    // 5,456,000 float4s
#define CHUNK 2707                           // ceil(N4 / FOCAL_BLOCKS); 11 rounds of 256
#define NROUND 11

// ws: partials @ 0 (2016 f32), imgstats @ 8192 (32 x {corr,loc,cnt} f32).
// Both fully written every call — no init required.
#define OFF_IMG 8192

typedef float f4v __attribute__((ext_vector_type(4)));

__device__ __forceinline__ float focal_elem(float x)
{
    float e  = __expf(-fabsf(x));                 // e^{-|x|}
    float t  = 1.f + e;
    float r  = __builtin_amdgcn_rcpf(t);          // ~1ulp rcp (2% output tolerance)
    float sp = fmaxf(x, 0.f) + __logf(t);         // softplus(x)
    float nm = (x >= 0.f) ? 1.f : e;
    float p  = nm * r;                            // sigmoid(x)
    return p * p * sp;
}

__device__ __forceinline__ float focal4v(f4v v)
{
    return focal_elem(v.x) + focal_elem(v.y) + focal_elem(v.z) + focal_elem(v.w);
}

// ------------------------------------------------------------------ kernel 1
// blocks [0, 2016): focal partial sums; NON-TEMPORAL loads (L1 bypass)
// blocks [2016, 2048): per-image scan (5x5 window) + decide
__global__ __launch_bounds__(256)
void atss_main(const float* __restrict__ locs,
               const float* __restrict__ scores,
               const float* __restrict__ boxes,
               const int*   __restrict__ labels,
               const float* __restrict__ priors,
               float* __restrict__ partials,
               float* __restrict__ imgstats)
{
    const int tid = threadIdx.x;
    const int blk = blockIdx.x;

    __shared__ float wsum[4];
    __shared__ float pov[KGT * 45];
    __shared__ int   tix[KGT * 45];
    __shared__ float sbox[KGT][4];
    __shared__ int   slab[KGT];
    __shared__ float thr[KGT];
    __shared__ float rc, rl;
    __shared__ int   rn;

    if (blk < FOCAL_BLOCKS) {
        // ---- focal base: sum p^2*softplus(x); streaming NT reads, 3-deep ----
        const f4v* s4 = (const f4v*)scores;
        const int cbase = blk * CHUNK;

        f4v buf[3];
        #pragma unroll
        for (int k = 0; k < 3; ++k)
            buf[k] = __builtin_nontemporal_load(
                         s4 + min(cbase + k * 256 + tid, N4 - 1));

        float a0 = 0.f, a1 = 0.f;
        #pragma unroll
        for (int k = 0; k < NROUND; ++k) {
            f4v v = buf[k % 3];
            if (k + 3 < NROUND)
                buf[k % 3] = __builtin_nontemporal_load(
                                 s4 + min(cbase + (k + 3) * 256 + tid, N4 - 1));
            // validity: k<=9 always inside chunk; k==10 iff tid < CHUNK-2560 (=147);
            // last block additionally clamped against N4.
            bool vld = (k * 256 + tid < CHUNK) && (cbase + k * 256 + tid < N4);
            float tv = focal4v(v);
            if (k & 1) a1 += vld ? tv : 0.f;
            else       a0 += vld ? tv : 0.f;
        }

        float lsum = a0 + a1;
        #pragma unroll
        for (int off = 32; off > 0; off >>= 1) lsum += __shfl_down(lsum, off);
        if ((tid & 63) == 0) wsum[tid >> 6] = lsum;
        __syncthreads();
        if (tid == 0)
            partials[blk] = wsum[0] + wsum[1] + wsum[2] + wsum[3];
        return;
    }

    // ---------------- scan + decide for image b, entirely block-local ----------
    const int b = blk - FOCAL_BLOCKS;
    const int SPLc[6] = {0, 6400, 8000, 8400, 8500, 8525};
    const int FDIM[5] = {80, 40, 20, 10, 5};

    if (tid == 0) { rc = 0.f; rl = 0.f; rn = 0; }
    if (tid < KGT) {
        float4 bxv = ((const float4*)boxes)[b * KGT + tid];
        sbox[tid][0] = bxv.x; sbox[tid][1] = bxv.y;
        sbox[tid][2] = bxv.z; sbox[tid][3] = bxv.w;
        slab[tid] = labels[b * KGT + tid];
    }
    __syncthreads();

    // Stage 1: one thread per (gt, level): top-9 via 5x5 grid window.
    // Priors of level l form a regular f x f grid, spacing 1/f: the 9 nearest
    // centers lie in the 5x5 window of nearest rows/cols (9th-nearest <= ~1.6/f,
    // anything outside >= 2.5/f).
    if (tid < KGT * NLVL) {
        const int g = tid / NLVL;
        const int l = tid % NLVL;
        const int f    = FDIM[l];
        const int base = SPLc[l];
        const float gcx = (sbox[g][0] + sbox[g][2]) * 0.5f;
        const float gcy = (sbox[g][1] + sbox[g][3]) * 0.5f;

        const float ff = (float)f;
        int ix0 = (int)floorf(gcx * ff); ix0 = min(max(ix0, 0), f - 1);
        int iy0 = (int)floorf(gcy * ff); iy0 = min(max(iy0, 0), f - 1);
        int sx = min(max(ix0 - 2, 0), f - 5);
        int sy = min(max(iy0 - 2, 0), f - 5);

        unsigned long long L[NCAND];
        #pragma unroll
        for (int s = 0; s < NCAND; ++s) L[s] = ~0ull;

        for (int dy = 0; dy < 5; ++dy) {
            for (int dx = 0; dx < 5; ++dx) {
                int idx = (sy + dy) * f + (sx + dx);
                float2 pc = ((const float2*)priors)[(base + idx) * 2];
                float ddx = gcx - pc.x, ddy = gcy - pc.y;
                float dist = sqrtf(ddx * ddx + ddy * ddy);  // matches ref rounding
                unsigned long long pk =
                    ((unsigned long long)__float_as_uint(dist) << 32) | (unsigned)idx;
                if (pk < L[NCAND - 1]) {            // lexicographic (dist, idx)
                    L[NCAND - 1] = pk;
                    #pragma unroll
                    for (int s = NCAND - 1; s >= 1; --s) {
                        if (L[s] < L[s - 1]) {
                            unsigned long long tw = L[s]; L[s] = L[s - 1]; L[s - 1] = tw;
                        } else break;
                    }
                }
            }
        }
        // ascending (dist, idx) == lax.top_k order; emit IoU per candidate
        #pragma unroll
        for (int s = 0; s < NCAND; ++s) {
            int idx = (int)(unsigned)(L[s] & 0xffffffffull);
            float4 pr = ((const float4*)priors)[base + idx];
            float px0 = pr.x - pr.z * 0.5f, py0 = pr.y - pr.w * 0.5f;
            float px1 = pr.x + pr.z * 0.5f, py1 = pr.y + pr.w * 0.5f;
            float iw = fmaxf(fminf(sbox[g][2], px1) - fmaxf(sbox[g][0], px0), 0.f);
            float ih = fmaxf(fminf(sbox[g][3], py1) - fmaxf(sbox[g][1], py0), 0.f);
            float inter = iw * ih;
            float areaA = (sbox[g][2] - sbox[g][0]) * (sbox[g][3] - sbox[g][1]);
            float areaP = (px1 - px0) * (py1 - py0);
            int o = g * 45 + l * NCAND + s;
            pov[o] = inter / (areaA + areaP - inter);
            tix[o] = idx;
        }
    }
    __syncthreads();

    // Stage 2: adaptive threshold = mean + std(ddof=1) over each GT's 45 IoUs
    if (tid < KGT) {
        float s = 0.f;
        for (int q = 0; q < 45; ++q) s += pov[tid * 45 + q];
        float mean = s / 45.f;
        float ss = 0.f;
        for (int q = 0; q < 45; ++q) { float d = pov[tid * 45 + q] - mean; ss += d * d; }
        thr[tid] = mean + sqrtf(ss / 44.f);
    }
    __syncthreads();

    // Stage 3: per (level, cand): argmax over GTs, focal correction + CIoU
    if (tid < NLVL * NCAND) {
        int l = tid / NCAND, j = tid % NCAND;
        float bestv = -1.f; int bestg = 0;
        #pragma unroll
        for (int gg = 0; gg < KGT; ++gg) {
            float m = pov[gg * 45 + tid];
            int pi = tix[gg * 45 + tid];
            float4 pr = ((const float4*)priors)[SPLc[l] + pi];
            bool inside = (sbox[gg][0] < pr.x) && (pr.x < sbox[gg][2]) &&
                          (sbox[gg][1] < pr.y) && (pr.y < sbox[gg][3]);
            float mm = ((m > thr[gg]) && inside) ? m : 0.f;
            if (mm > bestv) { bestv = mm; bestg = gg; }   // first max wins
        }
        if (bestv > 0.f) {
            int lab = slab[bestg];
            // focal correction at prior SPL[l]+j, class lab (ref's .at[arange(9)] quirk)
            long pos = (long)b * NPRI + SPLc[l] + j;
            float x  = scores[pos * NCLS + (lab - 1)];
            float e  = expf(-fabsf(x));
            float l1 = log1pf(e);
            float spp = fmaxf(x, 0.f) + l1;
            float spn = fmaxf(-x, 0.f) + l1;
            float p   = (x >= 0.f) ? 1.f / (1.f + e) : e / (1.f + e);
            float corr = 0.25f * (1.f - p) * (1.f - p) * spn - 0.75f * p * p * spp;

            // decode pred box at matched prior, CIoU vs gt
            int pi = tix[bestg * 45 + tid];
            float4 pr = ((const float4*)priors)[SPLc[l] + pi];
            float4 lc = ((const float4*)locs)[b * NPRI + SPLc[l] + pi];
            float cx = lc.x * pr.z / 10.f + pr.x;
            float cy = lc.y * pr.w / 10.f + pr.y;
            float w  = expf(lc.z / 5.f) * pr.z;
            float h  = expf(lc.w / 5.f) * pr.w;
            float qx0 = cx - w * 0.5f, qy0 = cy - h * 0.5f;
            float qx1 = cx + w * 0.5f, qy1 = cy + h * 0.5f;
            float gx0 = sbox[bestg][0], gy0 = sbox[bestg][1];
            float gx1 = sbox[bestg][2], gy1 = sbox[bestg][3];
            float w1 = qx1 - qx0, h1 = qy1 - qy0, w2 = gx1 - gx0, h2 = gy1 - gy0;
            float iw = fmaxf(fminf(qx1, gx1) - fmaxf(qx0, gx0), 0.f);
            float ih = fmaxf(fminf(qy1, gy1) - fmaxf(qy0, gy0), 0.f);
            float inter = iw * ih;
            float iou = inter / (w1 * h1 + w2 * h2 - inter);
            float dcx = (qx0 + qx1) * 0.5f - (gx0 + gx1) * 0.5f;
            float dcy = (qy0 + qy1) * 0.5f - (gy0 + gy1) * 0.5f;
            float rho2 = dcx * dcx + dcy * dcy;
            float ex = fmaxf(qx1, gx1) - fminf(qx0, gx0);
            float ey = fmaxf(qy1, gy1) - fminf(qy0, gy0);
            float cdiag = ex * ex + ey * ey;
            float da = atanf(w2 / h2) - atanf(w1 / h1);
            float v  = 0.4052847345693511f * da * da;     // 4/pi^2
            float alpha = v / (1.f - iou + v);
            float ci = iou - rho2 / cdiag - alpha * v;
            ci = fminf(fmaxf(ci, -1.f), 1.f);

            atomicAdd(&rc, corr);       // LDS atomics, block-local
            atomicAdd(&rl, 1.f - ci);
            atomicAdd(&rn, 1);
        }
    }
    __syncthreads();
    if (tid == 0) {
        imgstats[b * 3 + 0] = rc;
        imgstats[b * 3 + 1] = rl;
        imgstats[b * 3 + 2] = (float)rn;
    }
}

// ------------------------------------------------------------------ kernel 2
__global__ __launch_bounds__(256)
void atss_finalize(const float* __restrict__ partials,
                   const float* __restrict__ imgstats,
                   float* __restrict__ out)
{
    const int tid = threadIdx.x;
    __shared__ float wsum[4];
    float lsum = 0.f;
    for (int i = tid; i < FOCAL_BLOCKS; i += 256) lsum += partials[i];
    #pragma unroll
    for (int off = 32; off > 0; off >>= 1) lsum += __shfl_down(lsum, off);
    if ((tid & 63) == 0) wsum[tid >> 6] = lsum;
    __syncthreads();
    if (tid == 0) {
        float base = 0.75f * (wsum[0] + wsum[1] + wsum[2] + wsum[3]);
        float corr = 0.f, loc = 0.f, cnt = 0.f;
        for (int b = 0; b < NIMG; ++b) {
            corr += imgstats[b * 3 + 0];
            loc  += imgstats[b * 3 + 1];
            cnt  += imgstats[b * 3 + 2];
        }
        float conf = (base + corr) / cnt;            // ref: / n_pos (no clamp)
        float locl = loc / fmaxf(cnt, 1.f);          // ref: clamped denom
        out[0] = conf + locl;
    }
}

extern "C" void kernel_launch(void* const* d_in, const int* in_sizes, int n_in,
                              void* d_out, int out_size, void* d_ws, size_t ws_size,
                              hipStream_t stream)
{
    const float* locs   = (const float*)d_in[0];   // (32, 8525, 4)
    const float* scores = (const float*)d_in[1];   // (32, 8525, 80)
    const float* boxes  = (const float*)d_in[2];   // (32, 16, 4)
    const int*   labels = (const int*)d_in[3];     // (32, 16)
    const float* priors = (const float*)d_in[4];   // (8525, 4)
    float* out = (float*)d_out;

    float* partials = (float*)d_ws;
    float* imgstats = (float*)((char*)d_ws + OFF_IMG);

    atss_main<<<TOTAL_BLOCKS, 256, 0, stream>>>(locs, scores, boxes, labels,
                                                priors, partials, imgstats);
    atss_finalize<<<1, 256, 0, stream>>>(partials, imgstats, out);
}